// Round 1
// baseline (358.064 us; speedup 1.0000x reference)
//
#include <hip/hip_runtime.h>
#include <math.h>

#define C 256
#define S 4096
#define NH 8
#define DH 32
#define EPS 1e-5f
#define SCALE 0.17677669529663687f   // 1/sqrt(32)

// workspace layout (float offsets)
#define OFF_GW   0                        // 64*8*256 = 131072
#define OFF_G    (OFF_GW + 131072)        // 512
#define OFF_BC   (OFF_G + 512)            // 512
#define OFF_TT   (OFF_BC + 512)           // 64*8*4096 = 2097152 (scores -> tt in place)
#define OFF_RSTD (OFF_TT + 2097152)       // 262144
#define OFF_MUR  (OFF_RSTD + 262144)      // 262144
#define OFF_Z    (OFF_MUR + 262144)       // 512
#define OFF_M    (OFF_Z + 512)            // 131072

// ---------------------------------------------------------------------------
// K1: LN(mask_tokens) -> q -> fold q into Wk:  gw[h,c] = ln_p_w[c]*scale*(q^T Wk)[h,c]
//     plus per-(bn,h) constants G (sum_c gw') and Bc (bias term)
// ---------------------------------------------------------------------------
__global__ __launch_bounds__(256) void k1_prep(
    const float* __restrict__ mt, const float* __restrict__ ln_t_w, const float* __restrict__ ln_t_b,
    const float* __restrict__ ln_p_w, const float* __restrict__ ln_p_b,
    const float* __restrict__ Wq, const float* __restrict__ bq,
    const float* __restrict__ Wk, const float* __restrict__ bk,
    float* __restrict__ gw, float* __restrict__ Gv, float* __restrict__ Bc)
{
    int bn  = blockIdx.x;
    int tid = threadIdx.x;
    __shared__ float nt[C];
    __shared__ float qv[C];
    __shared__ float wks[NH][C];
    __shared__ float red[8];

    float x  = mt[bn * C + tid];
    float s1 = x, s2 = x * x;
    #pragma unroll
    for (int off = 32; off; off >>= 1) {
        s1 += __shfl_xor(s1, off);
        s2 += __shfl_xor(s2, off);
    }
    int wid = tid >> 6, lane = tid & 63;
    if (lane == 0) { red[wid] = s1; red[4 + wid] = s2; }
    __syncthreads();
    float mu   = (red[0] + red[1] + red[2] + red[3]) * (1.0f / C);
    float msq  = (red[4] + red[5] + red[6] + red[7]) * (1.0f / C);
    float rstd = rsqrtf(msq - mu * mu + EPS);
    nt[tid] = (x - mu) * rstd * ln_t_w[tid] + ln_t_b[tid];
    __syncthreads();

    // q[j] = nt . Wq[j,:] + bq[j]
    float acc = bq[tid];
    for (int c = 0; c < C; ++c) acc += nt[c] * Wq[(size_t)tid * C + c];
    qv[tid] = acc;
    __syncthreads();

    // wk_eff[h, c=tid] (scale folded in)
    int c = tid;
    #pragma unroll
    for (int h = 0; h < NH; ++h) {
        float a = 0.f;
        #pragma unroll
        for (int d = 0; d < DH; ++d) a += qv[h * DH + d] * Wk[(size_t)(h * DH + d) * C + c];
        a *= SCALE;
        wks[h][c] = a;
        gw[((size_t)bn * NH + h) * C + c] = ln_p_w[c] * a;
    }
    __syncthreads();
    if (tid < NH) {
        int h = tid;
        float g = 0.f, bsum = 0.f;
        for (int cc = 0; cc < C; ++cc) {
            g    += ln_p_w[cc] * wks[h][cc];
            bsum += ln_p_b[cc] * wks[h][cc];
        }
        float qbk = 0.f;
        for (int d = 0; d < DH; ++d) qbk += qv[h * DH + d] * bk[h * DH + d];
        Gv[bn * NH + h] = g;
        Bc[bn * NH + h] = bsum + qbk * SCALE;
    }
}

// ---------------------------------------------------------------------------
// K2 (pass A): stream pe [C,S] once per (b,n): per-s LN stats + 8 head scores.
// grid = 64 bn * 8 s-chunks(512) = 512 blocks, 256 threads, float2 per thread.
// ---------------------------------------------------------------------------
__global__ __launch_bounds__(256) void k2_scores(
    const float* __restrict__ pe, const float* __restrict__ gw,
    const float* __restrict__ Gv, const float* __restrict__ Bc,
    float* __restrict__ scores, float* __restrict__ rstd_o, float* __restrict__ mur_o)
{
    int blk   = blockIdx.x;
    int bn    = blk >> 3;
    int chunk = blk & 7;
    int b = bn >> 3, n = bn & 7;
    const float* x = pe + ((size_t)(n * 8 + b)) * C * S;
    int tid = threadIdx.x;
    int s   = chunk * 512 + tid * 2;

    __shared__ float gws[NH * C];
    for (int i = tid; i < NH * C; i += 256) gws[i] = gw[(size_t)bn * NH * C + i];
    __syncthreads();

    float2 sum = {0.f, 0.f}, sq = {0.f, 0.f};
    float2 A[NH];
    #pragma unroll
    for (int h = 0; h < NH; ++h) { A[h].x = 0.f; A[h].y = 0.f; }

    #pragma unroll 4
    for (int c = 0; c < C; ++c) {
        float2 xv = *reinterpret_cast<const float2*>(x + (size_t)c * S + s);
        sum.x += xv.x;        sum.y += xv.y;
        sq.x  += xv.x * xv.x; sq.y  += xv.y * xv.y;
        #pragma unroll
        for (int h = 0; h < NH; ++h) {
            float g = gws[h * C + c];
            A[h].x += g * xv.x; A[h].y += g * xv.y;
        }
    }
    float mux = sum.x * (1.f / C), muy = sum.y * (1.f / C);
    float vx  = sq.x * (1.f / C) - mux * mux;
    float vy  = sq.y * (1.f / C) - muy * muy;
    float rsx = rsqrtf(vx + EPS), rsy = rsqrtf(vy + EPS);
    float2 rs  = {rsx, rsy};
    float2 mur = {mux * rsx, muy * rsy};
    *reinterpret_cast<float2*>(rstd_o + (size_t)bn * S + s) = rs;
    *reinterpret_cast<float2*>(mur_o  + (size_t)bn * S + s) = mur;
    #pragma unroll
    for (int h = 0; h < NH; ++h) {
        float G = Gv[bn * NH + h], Bcv = Bc[bn * NH + h];
        float2 sc;
        sc.x = rsx * A[h].x - mur.x * G + Bcv;
        sc.y = rsy * A[h].y - mur.y * G + Bcv;
        *reinterpret_cast<float2*>(scores + ((size_t)(bn * NH + h)) * S + s) = sc;
    }
}

// ---------------------------------------------------------------------------
// K3: softmax over S per (bn,h); writes tt = attn*rstd in place, z = sum attn*mu*rstd
// ---------------------------------------------------------------------------
__global__ __launch_bounds__(256) void k3_softmax(
    float* __restrict__ scores, const float* __restrict__ rstd,
    const float* __restrict__ mur, float* __restrict__ z)
{
    int row = blockIdx.x;        // bn*8 + h
    int bn  = row >> 3;
    int tid = threadIdx.x;
    float* sc = scores + (size_t)row * S;

    float v[16];
    #pragma unroll
    for (int j = 0; j < 4; ++j) {
        float4 t = *reinterpret_cast<const float4*>(sc + j * 1024 + tid * 4);
        v[j*4+0] = t.x; v[j*4+1] = t.y; v[j*4+2] = t.z; v[j*4+3] = t.w;
    }
    float m = -1e30f;
    #pragma unroll
    for (int i = 0; i < 16; ++i) m = fmaxf(m, v[i]);
    #pragma unroll
    for (int off = 32; off; off >>= 1) m = fmaxf(m, __shfl_xor(m, off));
    __shared__ float red[4];
    int wid = tid >> 6, lane = tid & 63;
    if (lane == 0) red[wid] = m;
    __syncthreads();
    m = fmaxf(fmaxf(red[0], red[1]), fmaxf(red[2], red[3]));

    float l = 0.f;
    #pragma unroll
    for (int i = 0; i < 16; ++i) { v[i] = __expf(v[i] - m); l += v[i]; }
    #pragma unroll
    for (int off = 32; off; off >>= 1) l += __shfl_xor(l, off);
    __syncthreads();
    if (lane == 0) red[wid] = l;
    __syncthreads();
    l = red[0] + red[1] + red[2] + red[3];
    float inv = 1.f / l;

    float zp = 0.f;
    #pragma unroll
    for (int j = 0; j < 4; ++j) {
        int s4 = j * 1024 + tid * 4;
        float4 rsv = *reinterpret_cast<const float4*>(rstd + (size_t)bn * S + s4);
        float4 mrv = *reinterpret_cast<const float4*>(mur  + (size_t)bn * S + s4);
        float p0 = v[j*4+0] * inv, p1 = v[j*4+1] * inv, p2 = v[j*4+2] * inv, p3 = v[j*4+3] * inv;
        zp += p0 * mrv.x + p1 * mrv.y + p2 * mrv.z + p3 * mrv.w;
        float4 t = {p0 * rsv.x, p1 * rsv.y, p2 * rsv.z, p3 * rsv.w};
        *reinterpret_cast<float4*>(sc + s4) = t;
    }
    #pragma unroll
    for (int off = 32; off; off >>= 1) zp += __shfl_xor(zp, off);
    __syncthreads();
    if (lane == 0) red[wid] = zp;
    __syncthreads();
    if (tid == 0) z[row] = red[0] + red[1] + red[2] + red[3];
}

// ---------------------------------------------------------------------------
// K4 (pass B): M[h,c] = sum_s tt[h,s]*x[c,s]. grid = 64 bn * 4 c-quarters,
// 4 waves/block, each wave does 16 c-rows in groups of 4; butterfly reduce.
// bn order reversed to catch pass-A tail still resident in L3.
// ---------------------------------------------------------------------------
__global__ __launch_bounds__(256) void k4_weighted(
    const float* __restrict__ pe, const float* __restrict__ tt, float* __restrict__ M)
{
    int blk = blockIdx.x;
    int bn  = 63 - (blk >> 2);
    int cq  = blk & 3;
    int b = bn >> 3, n = bn & 7;
    int tid = threadIdx.x;
    int wid = tid >> 6, lane = tid & 63;
    const float* xb  = pe + ((size_t)(n * 8 + b)) * C * S;
    const float* ttb = tt + (size_t)bn * NH * S;

    for (int grp = 0; grp < 4; ++grp) {
        int c0 = cq * 64 + wid * 16 + grp * 4;
        float acc[4][NH];
        #pragma unroll
        for (int cc = 0; cc < 4; ++cc)
            #pragma unroll
            for (int h = 0; h < NH; ++h) acc[cc][h] = 0.f;

        for (int it = 0; it < 16; ++it) {
            int s = it * 256 + lane * 4;
            float4 tv[NH];
            #pragma unroll
            for (int h = 0; h < NH; ++h)
                tv[h] = *reinterpret_cast<const float4*>(ttb + (size_t)h * S + s);
            #pragma unroll
            for (int cc = 0; cc < 4; ++cc) {
                float4 xv = *reinterpret_cast<const float4*>(xb + (size_t)(c0 + cc) * S + s);
                #pragma unroll
                for (int h = 0; h < NH; ++h)
                    acc[cc][h] += xv.x*tv[h].x + xv.y*tv[h].y + xv.z*tv[h].z + xv.w*tv[h].w;
            }
        }
        #pragma unroll
        for (int cc = 0; cc < 4; ++cc)
            #pragma unroll
            for (int h = 0; h < NH; ++h)
                #pragma unroll
                for (int off = 32; off; off >>= 1)
                    acc[cc][h] += __shfl_xor(acc[cc][h], off);
        if (lane < 32) {
            int cc = lane >> 3, h = lane & 7;
            M[((size_t)bn * C + c0 + cc) * NH + h] = acc[cc][h];
        }
    }
}

// ---------------------------------------------------------------------------
// K5: weighted -> ctx -> Wo -> residual -> MLP -> out. One block per (b,n).
// ---------------------------------------------------------------------------
__global__ __launch_bounds__(256) void k5_out(
    const float* __restrict__ mt, const float* __restrict__ ln_p_w, const float* __restrict__ ln_p_b,
    const float* __restrict__ Mbuf, const float* __restrict__ z,
    const float* __restrict__ Wv, const float* __restrict__ bv,
    const float* __restrict__ Wo, const float* __restrict__ bo,
    const float* __restrict__ W1, const float* __restrict__ b1,
    const float* __restrict__ W2, const float* __restrict__ b2,
    float* __restrict__ out)
{
    int bn  = blockIdx.x;
    int tid = threadIdx.x;
    __shared__ float wei[NH * C];
    __shared__ float ctxs[C];
    __shared__ float upds[C];
    __shared__ float hid[2 * C];

    for (int idx = tid; idx < NH * C; idx += 256) {
        int h = idx >> 8;
        int c = idx & 255;
        wei[idx] = ln_p_w[c] * (Mbuf[((size_t)bn * C + c) * NH + h] - z[bn * NH + h]) + ln_p_b[c];
    }
    __syncthreads();

    {   // ctx[j] = weighted[h(j),:] . Wv[j,:] + bv[j]
        int h = tid >> 5;
        float a = bv[tid];
        const float* wrow = Wv + (size_t)tid * C;
        const float* wh   = wei + h * C;
        for (int c2 = 0; c2 < C; ++c2) a += wh[c2] * wrow[c2];
        ctxs[tid] = a;
    }
    __syncthreads();

    float att = bo[tid];
    {
        const float* wrow = Wo + (size_t)tid * C;
        for (int j = 0; j < C; ++j) att += ctxs[j] * wrow[j];
    }
    float upd = mt[(size_t)bn * C + tid] + att;
    upds[tid] = upd;
    __syncthreads();

    #pragma unroll
    for (int r = 0; r < 2; ++r) {
        int k = tid + r * 256;
        float a = b1[k];
        const float* wrow = W1 + (size_t)k * C;
        for (int c2 = 0; c2 < C; ++c2) a += upds[c2] * wrow[c2];
        hid[k] = fmaxf(a, 0.f);
    }
    __syncthreads();

    float a = b2[tid];
    const float* wrow = W2 + (size_t)tid * 2 * C;
    for (int k = 0; k < 2 * C; ++k) a += hid[k] * wrow[k];
    out[(size_t)bn * C + tid] = upd + a;
}

extern "C" void kernel_launch(void* const* d_in, const int* in_sizes, int n_in,
                              void* d_out, int out_size, void* d_ws, size_t ws_size,
                              hipStream_t stream)
{
    const float* mt  = (const float*)d_in[0];
    const float* pe  = (const float*)d_in[1];
    const float* ltw = (const float*)d_in[2];
    const float* ltb = (const float*)d_in[3];
    const float* lpw = (const float*)d_in[4];
    const float* lpb = (const float*)d_in[5];
    const float* Wq  = (const float*)d_in[6];
    const float* bq  = (const float*)d_in[7];
    const float* Wk  = (const float*)d_in[8];
    const float* bk  = (const float*)d_in[9];
    const float* Wv  = (const float*)d_in[10];
    const float* bv  = (const float*)d_in[11];
    const float* Wo  = (const float*)d_in[12];
    const float* bo  = (const float*)d_in[13];
    const float* W1  = (const float*)d_in[14];
    const float* b1  = (const float*)d_in[15];
    const float* W2  = (const float*)d_in[16];
    const float* b2  = (const float*)d_in[17];

    float* ws   = (float*)d_ws;
    float* outp = (float*)d_out;

    float* gw   = ws + OFF_GW;
    float* Gv   = ws + OFF_G;
    float* Bc   = ws + OFF_BC;
    float* tt   = ws + OFF_TT;
    float* rstd = ws + OFF_RSTD;
    float* mur  = ws + OFF_MUR;
    float* z    = ws + OFF_Z;
    float* M    = ws + OFF_M;

    k1_prep    <<<64,  256, 0, stream>>>(mt, ltw, ltb, lpw, lpb, Wq, bq, Wk, bk, gw, Gv, Bc);
    k2_scores  <<<512, 256, 0, stream>>>(pe, gw, Gv, Bc, tt, rstd, mur);
    k3_softmax <<<512, 256, 0, stream>>>(tt, rstd, mur, z);
    k4_weighted<<<256, 256, 0, stream>>>(pe, tt, M);
    k5_out     <<<64,  256, 0, stream>>>(mt, lpw, lpb, M, z, Wv, bv, Wo, bo, W1, b1, W2, b2, outp);
}

// Round 2
// 249.012 us; speedup vs baseline: 1.4379x; 1.4379x over previous
//
#include <hip/hip_runtime.h>
#include <math.h>

#define C 256
#define S 4096
#define NH 8
#define DH 32
#define EPS 1e-5f
#define SCALE 0.17677669529663687f   // 1/sqrt(32)

// workspace layout (float offsets)
#define OFF_GW   0                        // 64*8*256 = 131072
#define OFF_G    (OFF_GW + 131072)        // 512
#define OFF_BC   (OFF_G + 512)            // 512
#define OFF_TT   (OFF_BC + 512)           // 64*8*4096 = 2097152 (scores -> tt in place)
#define OFF_RSTD (OFF_TT + 2097152)       // 262144
#define OFF_MUR  (OFF_RSTD + 262144)      // 262144
#define OFF_Z    (OFF_MUR + 262144)       // 512
#define OFF_M    (OFF_Z + 512)            // 8*64*256*8 = 1048576 (s-chunk partials)

// ---------------------------------------------------------------------------
// K1: LN(mask_tokens) -> q -> fold q into Wk:  gw[h,c] = ln_p_w[c]*scale*(q^T Wk)[h,c]
//     plus per-(bn,h) constants G (sum_c gw') and Bc (bias term)
// ---------------------------------------------------------------------------
__global__ __launch_bounds__(256) void k1_prep(
    const float* __restrict__ mt, const float* __restrict__ ln_t_w, const float* __restrict__ ln_t_b,
    const float* __restrict__ ln_p_w, const float* __restrict__ ln_p_b,
    const float* __restrict__ Wq, const float* __restrict__ bq,
    const float* __restrict__ Wk, const float* __restrict__ bk,
    float* __restrict__ gw, float* __restrict__ Gv, float* __restrict__ Bc)
{
    int bn  = blockIdx.x;
    int tid = threadIdx.x;
    __shared__ float nt[C];
    __shared__ float qv[C];
    __shared__ float wks[NH][C];
    __shared__ float red[8];

    float x  = mt[bn * C + tid];
    float s1 = x, s2 = x * x;
    #pragma unroll
    for (int off = 32; off; off >>= 1) {
        s1 += __shfl_xor(s1, off);
        s2 += __shfl_xor(s2, off);
    }
    int wid = tid >> 6, lane = tid & 63;
    if (lane == 0) { red[wid] = s1; red[4 + wid] = s2; }
    __syncthreads();
    float mu   = (red[0] + red[1] + red[2] + red[3]) * (1.0f / C);
    float msq  = (red[4] + red[5] + red[6] + red[7]) * (1.0f / C);
    float rstd = rsqrtf(msq - mu * mu + EPS);
    nt[tid] = (x - mu) * rstd * ln_t_w[tid] + ln_t_b[tid];
    __syncthreads();

    // q[j] = nt . Wq[j,:] + bq[j]
    float acc = bq[tid];
    for (int c = 0; c < C; ++c) acc += nt[c] * Wq[(size_t)tid * C + c];
    qv[tid] = acc;
    __syncthreads();

    // wk_eff[h, c=tid] (scale folded in)
    int c = tid;
    #pragma unroll
    for (int h = 0; h < NH; ++h) {
        float a = 0.f;
        #pragma unroll
        for (int d = 0; d < DH; ++d) a += qv[h * DH + d] * Wk[(size_t)(h * DH + d) * C + c];
        a *= SCALE;
        wks[h][c] = a;
        gw[((size_t)bn * NH + h) * C + c] = ln_p_w[c] * a;
    }
    __syncthreads();
    if (tid < NH) {
        int h = tid;
        float g = 0.f, bsum = 0.f;
        for (int cc = 0; cc < C; ++cc) {
            g    += ln_p_w[cc] * wks[h][cc];
            bsum += ln_p_b[cc] * wks[h][cc];
        }
        float qbk = 0.f;
        for (int d = 0; d < DH; ++d) qbk += qv[h * DH + d] * bk[h * DH + d];
        Gv[bn * NH + h] = g;
        Bc[bn * NH + h] = bsum + qbk * SCALE;
    }
}

// ---------------------------------------------------------------------------
// K2 (pass A): stream pe [C,S] once per (b,n): per-s LN stats + 8 head scores.
// grid = 64 bn * 16 s-chunks(256) = 1024 blocks, 256 threads, 1 float/lane.
// gw tile staged transposed [c][h] so per-c reads are 2x ds_read_b128 broadcast.
// ---------------------------------------------------------------------------
__global__ __launch_bounds__(256) void k2_scores(
    const float* __restrict__ pe, const float* __restrict__ gw,
    const float* __restrict__ Gv, const float* __restrict__ Bc,
    float* __restrict__ scores, float* __restrict__ rstd_o, float* __restrict__ mur_o)
{
    int blk   = blockIdx.x;
    int bn    = blk >> 4;
    int chunk = blk & 15;
    int b = bn >> 3, n = bn & 7;
    const float* x = pe + ((size_t)(n * 8 + b)) * C * S;
    int tid = threadIdx.x;
    int s   = chunk * 256 + tid;

    __shared__ float gwt[C * NH];   // [c][h]
    for (int i = tid; i < NH * C; i += 256) {
        int h = i >> 8, c = i & 255;
        gwt[c * NH + h] = gw[(size_t)bn * NH * C + i];
    }
    __syncthreads();

    float sum = 0.f, sq = 0.f;
    float A[NH];
    #pragma unroll
    for (int h = 0; h < NH; ++h) A[h] = 0.f;

    #pragma unroll 4
    for (int c = 0; c < C; ++c) {
        float xv = x[(size_t)c * S + s];
        sum += xv;
        sq  += xv * xv;
        float4 g0 = *reinterpret_cast<const float4*>(&gwt[c * NH]);
        float4 g1 = *reinterpret_cast<const float4*>(&gwt[c * NH + 4]);
        A[0] += g0.x * xv; A[1] += g0.y * xv; A[2] += g0.z * xv; A[3] += g0.w * xv;
        A[4] += g1.x * xv; A[5] += g1.y * xv; A[6] += g1.z * xv; A[7] += g1.w * xv;
    }
    float mu  = sum * (1.f / C);
    float var = sq * (1.f / C) - mu * mu;
    float rs  = rsqrtf(var + EPS);
    float mur = mu * rs;
    rstd_o[(size_t)bn * S + s] = rs;
    mur_o [(size_t)bn * S + s] = mur;
    #pragma unroll
    for (int h = 0; h < NH; ++h) {
        float G = Gv[bn * NH + h], Bcv = Bc[bn * NH + h];
        scores[((size_t)(bn * NH + h)) * S + s] = rs * A[h] - mur * G + Bcv;
    }
}

// ---------------------------------------------------------------------------
// K3: softmax over S per (bn,h); writes tt = attn*rstd in place, z = sum attn*mu*rstd
// ---------------------------------------------------------------------------
__global__ __launch_bounds__(256) void k3_softmax(
    float* __restrict__ scores, const float* __restrict__ rstd,
    const float* __restrict__ mur, float* __restrict__ z)
{
    int row = blockIdx.x;        // bn*8 + h
    int bn  = row >> 3;
    int tid = threadIdx.x;
    float* sc = scores + (size_t)row * S;

    float v[16];
    #pragma unroll
    for (int j = 0; j < 4; ++j) {
        float4 t = *reinterpret_cast<const float4*>(sc + j * 1024 + tid * 4);
        v[j*4+0] = t.x; v[j*4+1] = t.y; v[j*4+2] = t.z; v[j*4+3] = t.w;
    }
    float m = -1e30f;
    #pragma unroll
    for (int i = 0; i < 16; ++i) m = fmaxf(m, v[i]);
    #pragma unroll
    for (int off = 32; off; off >>= 1) m = fmaxf(m, __shfl_xor(m, off));
    __shared__ float red[4];
    int wid = tid >> 6, lane = tid & 63;
    if (lane == 0) red[wid] = m;
    __syncthreads();
    m = fmaxf(fmaxf(red[0], red[1]), fmaxf(red[2], red[3]));

    float l = 0.f;
    #pragma unroll
    for (int i = 0; i < 16; ++i) { v[i] = __expf(v[i] - m); l += v[i]; }
    #pragma unroll
    for (int off = 32; off; off >>= 1) l += __shfl_xor(l, off);
    __syncthreads();
    if (lane == 0) red[wid] = l;
    __syncthreads();
    l = red[0] + red[1] + red[2] + red[3];
    float inv = 1.f / l;

    float zp = 0.f;
    #pragma unroll
    for (int j = 0; j < 4; ++j) {
        int s4 = j * 1024 + tid * 4;
        float4 rsv = *reinterpret_cast<const float4*>(rstd + (size_t)bn * S + s4);
        float4 mrv = *reinterpret_cast<const float4*>(mur  + (size_t)bn * S + s4);
        float p0 = v[j*4+0] * inv, p1 = v[j*4+1] * inv, p2 = v[j*4+2] * inv, p3 = v[j*4+3] * inv;
        zp += p0 * mrv.x + p1 * mrv.y + p2 * mrv.z + p3 * mrv.w;
        float4 t = {p0 * rsv.x, p1 * rsv.y, p2 * rsv.z, p3 * rsv.w};
        *reinterpret_cast<float4*>(sc + s4) = t;
    }
    #pragma unroll
    for (int off = 32; off; off >>= 1) zp += __shfl_xor(zp, off);
    __syncthreads();
    if (lane == 0) red[wid] = zp;
    __syncthreads();
    if (tid == 0) z[row] = red[0] + red[1] + red[2] + red[3];
}

// ---------------------------------------------------------------------------
// K4 (pass B): Mp[sc][bn][c][h] = sum_{s in chunk sc} tt[h,s]*x[c,s].
// grid = 64 bn * 4 cq * 8 sc = 2048 blocks (full occupancy). tt slice staged
// in LDS once per block. k5 folds the 8 partials.
// ---------------------------------------------------------------------------
__global__ __launch_bounds__(256) void k4_weighted(
    const float* __restrict__ pe, const float* __restrict__ tt, float* __restrict__ Mp)
{
    int blk   = blockIdx.x;
    int bn    = 63 - (blk >> 5);           // reversed for L3 reuse of pass-A tail
    int inner = blk & 31;
    int cq    = inner >> 3;
    int sc    = inner & 7;
    int b = bn >> 3, n = bn & 7;
    int tid = threadIdx.x;
    int wid = tid >> 6, lane = tid & 63;
    const float* xb  = pe + ((size_t)(n * 8 + b)) * C * S + sc * 512;
    const float* ttb = tt + (size_t)bn * NH * S + sc * 512;

    __shared__ float tls[NH * 512];
    #pragma unroll
    for (int i = 0; i < 4; ++i) {
        int flat = i * 1024 + tid * 4;
        int h = flat >> 9, off = flat & 511;
        *reinterpret_cast<float4*>(&tls[flat]) =
            *reinterpret_cast<const float4*>(ttb + (size_t)h * S + off);
    }
    __syncthreads();

    for (int grp = 0; grp < 4; ++grp) {
        int c0 = cq * 64 + wid * 16 + grp * 4;
        float acc[4][NH];
        #pragma unroll
        for (int cc = 0; cc < 4; ++cc)
            #pragma unroll
            for (int h = 0; h < NH; ++h) acc[cc][h] = 0.f;

        #pragma unroll
        for (int it = 0; it < 2; ++it) {
            int s = it * 256 + lane * 4;
            float4 tv[NH];
            #pragma unroll
            for (int h = 0; h < NH; ++h)
                tv[h] = *reinterpret_cast<const float4*>(&tls[h * 512 + s]);
            #pragma unroll
            for (int cc = 0; cc < 4; ++cc) {
                float4 xv = *reinterpret_cast<const float4*>(xb + (size_t)(c0 + cc) * S + s);
                #pragma unroll
                for (int h = 0; h < NH; ++h)
                    acc[cc][h] += xv.x*tv[h].x + xv.y*tv[h].y + xv.z*tv[h].z + xv.w*tv[h].w;
            }
        }
        #pragma unroll
        for (int cc = 0; cc < 4; ++cc)
            #pragma unroll
            for (int h = 0; h < NH; ++h)
                #pragma unroll
                for (int off = 32; off; off >>= 1)
                    acc[cc][h] += __shfl_xor(acc[cc][h], off);
        if (lane < 32) {
            int cc = lane >> 3, h = lane & 7;
            Mp[(((size_t)sc * 64 + bn) * C + c0 + cc) * NH + h] = acc[cc][h];
        }
    }
}

// ---------------------------------------------------------------------------
// K5: fold Mp partials -> weighted -> ctx -> Wo -> residual -> MLP -> out.
// ---------------------------------------------------------------------------
__global__ __launch_bounds__(256) void k5_out(
    const float* __restrict__ mt, const float* __restrict__ ln_p_w, const float* __restrict__ ln_p_b,
    const float* __restrict__ Mp, const float* __restrict__ z,
    const float* __restrict__ Wv, const float* __restrict__ bv,
    const float* __restrict__ Wo, const float* __restrict__ bo,
    const float* __restrict__ W1, const float* __restrict__ b1,
    const float* __restrict__ W2, const float* __restrict__ b2,
    float* __restrict__ out)
{
    int bn  = blockIdx.x;
    int tid = threadIdx.x;
    __shared__ float wei[NH * C];
    __shared__ float ctxs[C];
    __shared__ float upds[C];
    __shared__ float hid[2 * C];

    for (int idx = tid; idx < NH * C; idx += 256) {
        int h = idx >> 8;
        int c = idx & 255;
        float m = 0.f;
        #pragma unroll
        for (int sc = 0; sc < 8; ++sc)
            m += Mp[(((size_t)sc * 64 + bn) * C + c) * NH + h];
        wei[idx] = ln_p_w[c] * (m - z[bn * NH + h]) + ln_p_b[c];
    }
    __syncthreads();

    {   // ctx[j] = weighted[h(j),:] . Wv[j,:] + bv[j]
        int h = tid >> 5;
        float a = bv[tid];
        const float* wrow = Wv + (size_t)tid * C;
        const float* wh   = wei + h * C;
        for (int c2 = 0; c2 < C; ++c2) a += wh[c2] * wrow[c2];
        ctxs[tid] = a;
    }
    __syncthreads();

    float att = bo[tid];
    {
        const float* wrow = Wo + (size_t)tid * C;
        for (int j = 0; j < C; ++j) att += ctxs[j] * wrow[j];
    }
    float upd = mt[(size_t)bn * C + tid] + att;
    upds[tid] = upd;
    __syncthreads();

    #pragma unroll
    for (int r = 0; r < 2; ++r) {
        int k = tid + r * 256;
        float a = b1[k];
        const float* wrow = W1 + (size_t)k * C;
        for (int c2 = 0; c2 < C; ++c2) a += upds[c2] * wrow[c2];
        hid[k] = fmaxf(a, 0.f);
    }
    __syncthreads();

    float a = b2[tid];
    const float* wrow = W2 + (size_t)tid * 2 * C;
    for (int k = 0; k < 2 * C; ++k) a += hid[k] * wrow[k];
    out[(size_t)bn * C + tid] = upd + a;
}

extern "C" void kernel_launch(void* const* d_in, const int* in_sizes, int n_in,
                              void* d_out, int out_size, void* d_ws, size_t ws_size,
                              hipStream_t stream)
{
    const float* mt  = (const float*)d_in[0];
    const float* pe  = (const float*)d_in[1];
    const float* ltw = (const float*)d_in[2];
    const float* ltb = (const float*)d_in[3];
    const float* lpw = (const float*)d_in[4];
    const float* lpb = (const float*)d_in[5];
    const float* Wq  = (const float*)d_in[6];
    const float* bq  = (const float*)d_in[7];
    const float* Wk  = (const float*)d_in[8];
    const float* bk  = (const float*)d_in[9];
    const float* Wv  = (const float*)d_in[10];
    const float* bv  = (const float*)d_in[11];
    const float* Wo  = (const float*)d_in[12];
    const float* bo  = (const float*)d_in[13];
    const float* W1  = (const float*)d_in[14];
    const float* b1  = (const float*)d_in[15];
    const float* W2  = (const float*)d_in[16];
    const float* b2  = (const float*)d_in[17];

    float* ws   = (float*)d_ws;
    float* outp = (float*)d_out;

    float* gw   = ws + OFF_GW;
    float* Gv   = ws + OFF_G;
    float* Bc   = ws + OFF_BC;
    float* tt   = ws + OFF_TT;
    float* rstd = ws + OFF_RSTD;
    float* mur  = ws + OFF_MUR;
    float* z    = ws + OFF_Z;
    float* Mp   = ws + OFF_M;

    k1_prep    <<<64,   256, 0, stream>>>(mt, ltw, ltb, lpw, lpb, Wq, bq, Wk, bk, gw, Gv, Bc);
    k2_scores  <<<1024, 256, 0, stream>>>(pe, gw, Gv, Bc, tt, rstd, mur);
    k3_softmax <<<512,  256, 0, stream>>>(tt, rstd, mur, z);
    k4_weighted<<<2048, 256, 0, stream>>>(pe, tt, Mp);
    k5_out     <<<64,   256, 0, stream>>>(mt, lpw, lpb, Mp, z, Wv, bv, Wo, bo, W1, b1, W2, b2, outp);
}